// Round 15
// baseline (844.545 us; speedup 1.0000x reference)
//
#include <hip/hip_runtime.h>

typedef unsigned int UI;
typedef unsigned long long ULL;
typedef _Float16 f16;
typedef _Float16 h8 __attribute__((ext_vector_type(8)));
typedef float f32x4 __attribute__((ext_vector_type(4)));
typedef float fl2 __attribute__((ext_vector_type(2)));

#define NB_PTS 4096
#define MB_SEL 1024
#define KNBR   64
#define NCLOUD 4
#define NCENT  4096

// ws layout (f16): Wt1[128][96] @0 ; Wt2[128][128] @12288 ; Wt3[256][128] @28672
#define WT2_OFF 12288
#define WT3_OFF 28672
#define WS_ELEMS 61440
#define WSFLAG_MAGIC 0x1234ABCDu   // != 0 (memset) and != 0xAAAAAAAA (poison)

// dynamic-LDS layout (bytes). conv view (all < 50 KB):
#define OFF_H1   13312   // h1s [64*136 f16]
#define OFF_H2   30720   // h2s [64*136 f16]
#define OFF_PMAX 48128   // pmax [256 f32]
#define OFF_MASK 49152   // masks [64 ULL]
#define OFF_NBR  49664   // nbrS [64 int]
#define OFF_NV   49920   // nvS int
#define OFF_SHS  49924   // spun sel int
// fps view: pp float4[4096] @0 (64 KB), slots ULL[2][8] @65536
#define OFF_SLOT 65536
// 84 KB > 160/2 KB  =>  exactly ONE block per CU (fps CUs run interference-free)
#define DYN_LDS  86016

// exact np-order squared distance, f64 (radius predicate — proven)
__device__ __forceinline__ double d2_np64(double dx, double dy, double dz) {
  return __dadd_rn(__dadd_rn(__dmul_rn(dx, dx), __dmul_rn(dy, dy)),
                   __dmul_rn(dz, dz));
}

// one u64-max DPP step (r10 exact; bound_ctrl=1 -> OOB lanes read 0, never wins)
template <int CTRL>
__device__ __forceinline__ ULL dpp_max_step(ULL cur) {
  UI lo = (UI)cur, hi = (UI)(cur >> 32);
  UI nl = (UI)__builtin_amdgcn_update_dpp(0, (int)lo, CTRL, 0xf, 0xf, true);
  UI nh = (UI)__builtin_amdgcn_update_dpp(0, (int)hi, CTRL, 0xf, 0xf, true);
  ULL nv = ((ULL)nh << 32) | (ULL)nl;
  return nv > cur ? nv : cur;
}

// ---------------------------------------------------------------------------
// ONE fused kernel, 512-thr blocks, 1 block/CU (84 KB dynamic LDS).
// blocks 0..3: FPS — barrier-FREE: double-buffered seq-stamped LDS slots,
//   wave-skew provably <= 1 iter, slot key = [dist:32][4095-idx:12][seq:10].
// block 4: weight prep (f32 -> f16 transposed [n][k]) + release flag.
// blocks 5..4100: conv centroid c=idx-5 (r14-proven bitwise path).
// ---------------------------------------------------------------------------
__global__ __launch_bounds__(512, 2) void fused_kernel(
    const float* __restrict__ x, const float* __restrict__ pos,
    const float* __restrict__ W1, const float* __restrict__ b1,
    const float* __restrict__ W2, const float* __restrict__ b2,
    const float* __restrict__ W3, const float* __restrict__ b3,
    f16* __restrict__ ws, UI* __restrict__ wsflag,
    float* __restrict__ selstash, float* __restrict__ out_x,
    float* __restrict__ out_pos, float* __restrict__ out_batch) {
  extern __shared__ char smem[];
  const int tid  = threadIdx.x;
  const int lane = tid & 63;
  const int wv   = tid >> 6;

  // ======================= role: weight prep (block 4) =====================
  if (blockIdx.x == NCLOUD) {
    for (int t = tid; t < WS_ELEMS; t += 512) {
      if (t < WT2_OFF) {                       // Wt1[n][k] : 128 x 96
        int n = t / 96, k = t - n * 96;
        ws[t] = (k < 67) ? (f16)W1[k * 128 + n] : (f16)0.f;
      } else if (t < WT3_OFF) {                // Wt2[n][k] : 128 x 128
        int u = t - WT2_OFF;
        int n = u >> 7, k = u & 127;
        ws[t] = (f16)W2[k * 128 + n];
      } else {                                 // Wt3[n][k] : 256 x 128
        int u = t - WT3_OFF;
        int n = u >> 7, k = u & 127;
        ws[t] = (f16)W3[k * 256 + n];
      }
    }
    __syncthreads();   // drains all waves' stores before publishing
    if (tid == 0)
      __hip_atomic_store(wsflag, WSFLAG_MAGIC, __ATOMIC_RELEASE,
                         __HIP_MEMORY_SCOPE_AGENT);
    return;
  }

  // ============================ role: FPS (0..3) ===========================
  if (blockIdx.x < NCLOUD) {
#pragma clang fp contract(off)
    asm volatile("s_setprio 3");
    float4* pp = (float4*)smem;                // 64 KB
    ULL* slots = (ULL*)(smem + OFF_SLOT);      // [2][8] flat
    const int b = blockIdx.x;

    fl2 mx[4], my[4], mz[4], dist[4];
#pragma unroll
    for (int t = 0; t < 4; ++t) {
      int j0 = tid + (2 * t) * 512;
      int j1 = tid + (2 * t + 1) * 512;
      size_t a0 = ((size_t)b * NB_PTS + j0) * 3;
      size_t a1 = ((size_t)b * NB_PTS + j1) * 3;
      float X0 = pos[a0], Y0 = pos[a0 + 1], Z0 = pos[a0 + 2];
      float X1 = pos[a1], Y1 = pos[a1 + 1], Z1 = pos[a1 + 2];
      pp[j0] = make_float4(X0, Y0, Z0, 0.f);
      pp[j1] = make_float4(X1, Y1, Z1, 0.f);
      mx[t] = fl2{X0, X1}; my[t] = fl2{Y0, Y1}; mz[t] = fl2{Z0, Z1};
      dist[t] = fl2{__builtin_inff(), __builtin_inff()};
    }
    if (tid < 16) slots[tid] = 0ull;   // seq 0: never matches k in [1,1023]
    if (tid == 0)
      __hip_atomic_store(&selstash[b * MB_SEL], 1.0f, __ATOMIC_RELAXED,
                         __HIP_MEMORY_SCOPE_AGENT);   // sel 0, encoded +1
    __syncthreads();   // pp + slots visible to all waves (the ONLY barrier)

    int cur = 0;
    for (int k = 1; k < MB_SEL; ++k) {
      float4 w = pp[cur];               // one b128 broadcast read
      float bestv = -__builtin_inff();
      int   besti = 0x7fffffff;
#pragma unroll
      for (int t = 0; t < 4; ++t) {
        fl2 dx = mx[t] - w.x;           // v_pk ops; per-comp RN == scalar np
        fl2 dy = my[t] - w.y;
        fl2 dz = mz[t] - w.z;
        fl2 dd = (dx * dx + dy * dy) + dz * dz;   // np order, contract off
        fl2 dc = dist[t];
        float d0 = fminf(dc.x, dd.x);   // np.minimum
        float d1 = fminf(dc.y, dd.y);
        dist[t] = fl2{d0, d1};
        if (d0 > bestv) { bestv = d0; besti = tid + (2 * t) * 512; }
        if (d1 > bestv) { bestv = d1; besti = tid + (2 * t + 1) * 512; }
      }
      // intra-wave: u64 key (larger d wins; tie -> smaller idx)
      ULL key = ((ULL)__float_as_uint(bestv) << 32) | (ULL)(~(UI)besti);
      key = dpp_max_step<0x111>(key);   // row_shr:1
      key = dpp_max_step<0x112>(key);   // row_shr:2
      key = dpp_max_step<0x114>(key);   // row_shr:4
      key = dpp_max_step<0x118>(key);   // row_shr:8
      key = dpp_max_step<0x142>(key);   // row_bcast:15
      key = dpp_max_step<0x143>(key);   // row_bcast:31 -> lane 63 = wave max
      // cross-wave: seq-stamped slot, NO barrier.
      // slot = [dist:32][4095-idx:12]<<10 | (k&0x3FF); equal-seq compare
      // preserves (max dist, then min idx) ordering.
      const UI seq = (UI)k & 0x3FFu;
      const int buf = (k & 1) * 8;
      if (lane == 63) {
        UI wdist = (UI)(key >> 32);
        UI widx  = ~(UI)key;            // wave-winner index (fits 12 bits)
        ULL slotv = ((ULL)wdist << 32) | ((ULL)(4095u - widx) << 10) | seq;
        __hip_atomic_store(&slots[buf + wv], slotv, __ATOMIC_RELAXED,
                           __HIP_MEMORY_SCOPE_WORKGROUP);
      }
      ULL s[8];
      for (;;) {
        bool ok = true;
#pragma unroll
        for (int i = 0; i < 8; ++i) {
          s[i] = __hip_atomic_load(&slots[buf + i], __ATOMIC_RELAXED,
                                   __HIP_MEMORY_SCOPE_WORKGROUP);
          ok &= ((UI)s[i] & 0x3FFu) == seq;
        }
        if (ok) break;
        __builtin_amdgcn_s_sleep(1);
      }
      ULL m01 = s[0] > s[1] ? s[0] : s[1];
      ULL m23 = s[2] > s[3] ? s[2] : s[3];
      ULL m45 = s[4] > s[5] ? s[4] : s[5];
      ULL m67 = s[6] > s[7] ? s[6] : s[7];
      ULL ma = m01 > m23 ? m01 : m23;
      ULL mb = m45 > m67 ? m45 : m67;
      ULL mk = ma > mb ? ma : mb;
      int winner = 4095 - (int)((mk >> 10) & 0xFFFu);
      if (tid == 0)
        __hip_atomic_store(&selstash[b * MB_SEL + k], (float)(winner + 1),
                           __ATOMIC_RELAXED, __HIP_MEMORY_SCOPE_AGENT);
      cur = winner;
    }
    return;
  }

  // ============================ role: conv =================================
  f16* featA  = (f16*)smem;
  f16* h1s    = (f16*)(smem + OFF_H1);
  f16* h2s    = (f16*)(smem + OFF_H2);
  float* pmax = (float*)(smem + OFF_PMAX);
  ULL* masks  = (ULL*)(smem + OFF_MASK);
  int* nbrS   = (int*)(smem + OFF_NBR);
  int* nvP    = (int*)(smem + OFF_NV);
  int* shS    = (int*)(smem + OFF_SHS);

  const int c  = (int)blockIdx.x - (NCLOUD + 1);
  const int k  = c >> 2;
  const int b  = c & 3;
  const int cg = b * MB_SEL + k;     // global centroid id (output index)

  // gate 1: weights ready (release/acquire covers the non-atomic ws payload)
  if (tid == 0) {
    while (__hip_atomic_load(wsflag, __ATOMIC_ACQUIRE,
                             __HIP_MEMORY_SCOPE_AGENT) != WSFLAG_MAGIC)
      __builtin_amdgcn_s_sleep(2);
  }
  __syncthreads();

  // B1/B2 + bias preload (8 waves own 16 cols each for L1/L2, 32 for L3)
  const int n    = lane & 15;
  const int quad = lane >> 4;
  const int col  = wv * 16 + n;       // L1/L2 column
  h8 B1f[3], B2f[4];
  float bv1, bv2, bv3[2];
  bv1 = b1[col];
  bv2 = b2[col];
#pragma unroll
  for (int kt = 0; kt < 3; ++kt)
    B1f[kt] = *(const h8*)(ws + col * 96 + kt * 32 + quad * 8);
#pragma unroll
  for (int kt = 0; kt < 4; ++kt)
    B2f[kt] = *(const h8*)(ws + WT2_OFF + col * 128 + kt * 32 + quad * 8);
#pragma unroll
  for (int ct = 0; ct < 2; ++ct) bv3[ct] = b3[(2 * wv + ct) * 16 + n];

  // gate 2: own sel ready (value IS the payload; winner+1 >= 1;
  // both init states — memset-0 and 0xAA poison — read as "not ready")
  if (tid == 0) {
    float v;
    for (;;) {
      v = __hip_atomic_load(&selstash[cg], __ATOMIC_RELAXED,
                            __HIP_MEMORY_SCOPE_AGENT);
      if (v >= 1.0f) break;
      __builtin_amdgcn_s_sleep(8);
    }
    *shS = (int)v - 1;
  }
  __syncthreads();
  const int s = (*shS) & (NB_PTS - 1);

  const size_t qb = ((size_t)(b * NB_PTS + s)) * 3;
  const float qxf = pos[qb], qyf = pos[qb + 1], qzf = pos[qb + 2];
  const double qx = (double)qxf, qy = (double)qyf, qz = (double)qzf;
  const double RR = 0.2 * 0.2;

  // radius: in-ball bitmask over all 4096 points (f64, np-exact).
  // 8 waves x 8 chunks = 64 chunks of 64 points.
#pragma unroll
  for (int it = 0; it < 8; ++it) {
    const int ch = wv * 8 + it;
    const int j  = ch * 64 + lane;
    const size_t pb = ((size_t)b * NB_PTS + j) * 3;
    double d2 = d2_np64((double)pos[pb] - qx, (double)pos[pb + 1] - qy,
                        (double)pos[pb + 2] - qz);
    ULL m = __ballot(d2 <= RR);
    if (lane == 0) masks[ch] = m;
  }
  __syncthreads();

  // wave 0: first-64 in-ball extraction (ascending index)
  if (tid < 64) {
    ULL m = masks[tid];
    int pc = __popcll(m);
    int incl = pc;
#pragma unroll
    for (int off = 1; off < 64; off <<= 1) {
      int o = __shfl_up(incl, off, 64);
      if (tid >= off) incl += o;
    }
    int base = incl - pc;
    int tot  = __shfl(incl, 63, 64);
    int nvw  = min(tot, KNBR);
    if (tid == 63) *nvP = nvw;
    int slot = base;
    ULL mm = m;
    while (mm && slot < KNBR) {
      int bit = __ffsll(mm) - 1;
      nbrS[slot++] = tid * 64 + bit;
      mm &= mm - 1;
    }
    if (tid >= nvw) nbrS[tid] = s;
  }
  __syncthreads();
  const int nv = *nvP;

  // gather: feat=[x_j, pos_j-pos_i, 0-pad] as f16, rows 0..63 (8 thr/row)
  {
    const int r = tid >> 3;
    const int part = tid & 7;
    const int g = nbrS[r];
    const float* xrow = x + (((size_t)(b * NB_PTS + g)) << 6) + part * 8;
    float4 u0 = *(const float4*)(xrow);
    float4 u1 = *(const float4*)(xrow + 4);
    h8 o0;
    o0[0]=(f16)u0.x; o0[1]=(f16)u0.y; o0[2]=(f16)u0.z; o0[3]=(f16)u0.w;
    o0[4]=(f16)u1.x; o0[5]=(f16)u1.y; o0[6]=(f16)u1.z; o0[7]=(f16)u1.w;
    *(h8*)(featA + r * 104 + part * 8) = o0;
    if (part == 7) {
      size_t gb = ((size_t)(b * NB_PTS + g)) * 3;
      h8 rv = {(f16)0.f,(f16)0.f,(f16)0.f,(f16)0.f,(f16)0.f,(f16)0.f,(f16)0.f,(f16)0.f};
      rv[0] = (f16)(pos[gb]     - qxf);
      rv[1] = (f16)(pos[gb + 1] - qyf);
      rv[2] = (f16)(pos[gb + 2] - qzf);
      h8 z = {(f16)0.f,(f16)0.f,(f16)0.f,(f16)0.f,(f16)0.f,(f16)0.f,(f16)0.f,(f16)0.f};
      *(h8*)(featA + r * 104 + 64) = rv;
      *(h8*)(featA + r * 104 + 72) = z;
      *(h8*)(featA + r * 104 + 80) = z;
      *(h8*)(featA + r * 104 + 88) = z;
    }
  }
  __syncthreads();

  // L1: 67(->96) -> 128 ; wave w owns cols [16w,16w+16)
#pragma unroll
  for (int at = 0; at < 4; ++at) {
    f32x4 acc = {0.f, 0.f, 0.f, 0.f};
#pragma unroll
    for (int kt = 0; kt < 3; ++kt) {
      h8 a = *(const h8*)(featA + (at * 16 + n) * 104 + kt * 32 + quad * 8);
      acc = __builtin_amdgcn_mfma_f32_16x16x32_f16(a, B1f[kt], acc, 0, 0, 0);
    }
#pragma unroll
    for (int r = 0; r < 4; ++r)
      h1s[(at * 16 + quad * 4 + r) * 136 + col] = (f16)fmaxf(acc[r] + bv1, 0.f);
  }
  __syncthreads();

  // L2: 128 -> 128
#pragma unroll
  for (int at = 0; at < 4; ++at) {
    f32x4 acc = {0.f, 0.f, 0.f, 0.f};
#pragma unroll
    for (int kt = 0; kt < 4; ++kt) {
      h8 a = *(const h8*)(h1s + (at * 16 + n) * 136 + kt * 32 + quad * 8);
      acc = __builtin_amdgcn_mfma_f32_16x16x32_f16(a, B2f[kt], acc, 0, 0, 0);
    }
#pragma unroll
    for (int r = 0; r < 4; ++r)
      h2s[(at * 16 + quad * 4 + r) * 136 + col] = (f16)fmaxf(acc[r] + bv2, 0.f);
  }
  __syncthreads();

  // L3: 128 -> 256, wave w owns cols [32w,32w+32); B3 streamed from L2
  float vm[2] = {0.f, 0.f};   // valid max >= 0 (relu, nv>=1)
#pragma unroll
  for (int at = 0; at < 4; ++at) {
#pragma unroll
    for (int ct = 0; ct < 2; ++ct) {
      const int c3 = (2 * wv + ct) * 16 + n;
      f32x4 acc = {0.f, 0.f, 0.f, 0.f};
#pragma unroll
      for (int kt = 0; kt < 4; ++kt) {
        h8 a = *(const h8*)(h2s + (at * 16 + n) * 136 + kt * 32 + quad * 8);
        h8 wfr = *(const h8*)(ws + WT3_OFF + c3 * 128 + kt * 32 + quad * 8);
        acc = __builtin_amdgcn_mfma_f32_16x16x32_f16(a, wfr, acc, 0, 0, 0);
      }
#pragma unroll
      for (int r = 0; r < 4; ++r) {
        float h = fmaxf(acc[r] + bv3[ct], 0.f);
        const int row = at * 16 + quad * 4 + r;
        vm[ct] = fmaxf(vm[ct], row < nv ? h : 0.f);
      }
    }
  }
#pragma unroll
  for (int ct = 0; ct < 2; ++ct) {
    vm[ct] = fmaxf(vm[ct], __shfl_xor(vm[ct], 16, 64));
    vm[ct] = fmaxf(vm[ct], __shfl_xor(vm[ct], 32, 64));
  }
  if (quad == 0) {
#pragma unroll
    for (int ct = 0; ct < 2; ++ct) pmax[(2 * wv + ct) * 16 + n] = vm[ct];
  }
  __syncthreads();

  if (tid < 256) out_x[(size_t)cg * 256 + tid] = pmax[tid];
  if (tid < 3) out_pos[cg * 3 + tid] = pos[qb + tid];
  if (tid == 0) out_batch[cg] = (float)b;   // overwrite sel stash
}

extern "C" void kernel_launch(void* const* d_in, const int* in_sizes, int n_in,
                              void* d_out, int out_size, void* d_ws, size_t ws_size,
                              hipStream_t stream) {
  const float* x   = (const float*)d_in[0];
  const float* pos = (const float*)d_in[1];
  // d_in[2] = batch (int32), unused (layout known)
  const float* W1 = (const float*)d_in[3];
  const float* b1 = (const float*)d_in[4];
  const float* W2 = (const float*)d_in[5];
  const float* b2 = (const float*)d_in[6];
  const float* W3 = (const float*)d_in[7];
  const float* b3 = (const float*)d_in[8];

  float* out = (float*)d_out;
  float* out_pos   = out + (size_t)NCENT * 256;
  float* out_batch = out_pos + (size_t)NCENT * 3;   // doubles as sel channel
  f16* ws    = (f16*)d_ws;                          // 122880 B f16 weights
  UI* wsflag = (UI*)((char*)d_ws + 2 * WS_ELEMS);   // publish flag

  // opt-in to >64 KB dynamic LDS (idempotent; host-side, capture-safe)
  hipFuncSetAttribute((const void*)fused_kernel,
                      hipFuncAttributeMaxDynamicSharedMemorySize, DYN_LDS);

  fused_kernel<<<NCLOUD + 1 + NCENT, 512, DYN_LDS, stream>>>(
      x, pos, W1, b1, W2, b2, W3, b3, ws, wsflag,
      out_batch, out, out_pos, out_batch);
}

// Round 16
// 722.693 us; speedup vs baseline: 1.1686x; 1.1686x over previous
//
#include <hip/hip_runtime.h>

typedef unsigned int UI;
typedef unsigned long long ULL;
typedef _Float16 f16;
typedef _Float16 h8 __attribute__((ext_vector_type(8)));
typedef float f32x4 __attribute__((ext_vector_type(4)));
typedef float fl2 __attribute__((ext_vector_type(2)));

#define NB_PTS 4096
#define MB_SEL 1024
#define KNBR   64
#define NCLOUD 4
#define NCENT  4096

// ws layout (f16): Wt1[128][96] @0 ; Wt2[128][128] @12288 ; Wt3[256][128] @28672
#define WT2_OFF 12288
#define WT3_OFF 28672
#define WS_ELEMS 61440
#define WSFLAG_MAGIC 0x1234ABCDu   // != 0 (memset) and != 0xAAAAAAAA (poison)

// dynamic-LDS layout (bytes). conv view (all < 50 KB):
#define OFF_H1   13312   // h1s [64*136 f16]
#define OFF_H2   30720   // h2s [64*136 f16]
#define OFF_PMAX 48128   // pmax [256 f32]
#define OFF_MASK 49152   // masks [64 ULL]
#define OFF_NBR  49664   // nbrS [64 int]
#define OFF_NV   49920   // nvS int
#define OFF_SHS  49924   // spun sel int
// fps view: pp float4[4096] @0 (64 KB), slots ULL[2][8] @65536
#define OFF_SLOT 65536
// 84 KB > 160/2 KB  =>  exactly ONE block per CU (fps CUs run interference-free)
#define DYN_LDS  86016

// exact np-order squared distance, f64 (radius predicate — proven)
__device__ __forceinline__ double d2_np64(double dx, double dy, double dz) {
  return __dadd_rn(__dadd_rn(__dmul_rn(dx, dx), __dmul_rn(dy, dy)),
                   __dmul_rn(dz, dz));
}

// one u64-max DPP step (r10 exact; bound_ctrl=1 -> OOB lanes read 0, never wins)
template <int CTRL>
__device__ __forceinline__ ULL dpp_max_step(ULL cur) {
  UI lo = (UI)cur, hi = (UI)(cur >> 32);
  UI nl = (UI)__builtin_amdgcn_update_dpp(0, (int)lo, CTRL, 0xf, 0xf, true);
  UI nh = (UI)__builtin_amdgcn_update_dpp(0, (int)hi, CTRL, 0xf, 0xf, true);
  ULL nv = ((ULL)nh << 32) | (ULL)nl;
  return nv > cur ? nv : cur;
}

// ---------------------------------------------------------------------------
// ONE fused kernel, 512-thr blocks, 1 block/CU (84 KB dynamic LDS).
// blocks 0..3: FPS (r14-exact: 512 thr x 8 pts, DPP wave-reduce, LDS slots,
//   single s_barrier per iteration — best of 6 sync topologies tested).
// block 4: weight prep (f32 -> f16 transposed [n][k]) + release flag.
// blocks 5..4100: conv centroid c=idx-5 (r14-proven bitwise path).
// ---------------------------------------------------------------------------
__global__ __launch_bounds__(512, 2) void fused_kernel(
    const float* __restrict__ x, const float* __restrict__ pos,
    const float* __restrict__ W1, const float* __restrict__ b1,
    const float* __restrict__ W2, const float* __restrict__ b2,
    const float* __restrict__ W3, const float* __restrict__ b3,
    f16* __restrict__ ws, UI* __restrict__ wsflag,
    float* __restrict__ selstash, float* __restrict__ out_x,
    float* __restrict__ out_pos, float* __restrict__ out_batch) {
  extern __shared__ char smem[];
  const int tid  = threadIdx.x;
  const int lane = tid & 63;
  const int wv   = tid >> 6;

  // ======================= role: weight prep (block 4) =====================
  if (blockIdx.x == NCLOUD) {
    for (int t = tid; t < WS_ELEMS; t += 512) {
      if (t < WT2_OFF) {                       // Wt1[n][k] : 128 x 96
        int n = t / 96, k = t - n * 96;
        ws[t] = (k < 67) ? (f16)W1[k * 128 + n] : (f16)0.f;
      } else if (t < WT3_OFF) {                // Wt2[n][k] : 128 x 128
        int u = t - WT2_OFF;
        int n = u >> 7, k = u & 127;
        ws[t] = (f16)W2[k * 128 + n];
      } else {                                 // Wt3[n][k] : 256 x 128
        int u = t - WT3_OFF;
        int n = u >> 7, k = u & 127;
        ws[t] = (f16)W3[k * 256 + n];
      }
    }
    __syncthreads();   // drains all waves' stores before publishing
    if (tid == 0)
      __hip_atomic_store(wsflag, WSFLAG_MAGIC, __ATOMIC_RELEASE,
                         __HIP_MEMORY_SCOPE_AGENT);
    return;
  }

  // ============================ role: FPS (0..3) ===========================
  if (blockIdx.x < NCLOUD) {
#pragma clang fp contract(off)
    asm volatile("s_setprio 3");
    float4* pp = (float4*)smem;                // 64 KB
    ULL* slots = (ULL*)(smem + OFF_SLOT);      // [2][8]
    const int b = blockIdx.x;

    fl2 mx[4], my[4], mz[4], dist[4];
#pragma unroll
    for (int t = 0; t < 4; ++t) {
      int j0 = tid + (2 * t) * 512;
      int j1 = tid + (2 * t + 1) * 512;
      size_t a0 = ((size_t)b * NB_PTS + j0) * 3;
      size_t a1 = ((size_t)b * NB_PTS + j1) * 3;
      float X0 = pos[a0], Y0 = pos[a0 + 1], Z0 = pos[a0 + 2];
      float X1 = pos[a1], Y1 = pos[a1 + 1], Z1 = pos[a1 + 2];
      pp[j0] = make_float4(X0, Y0, Z0, 0.f);
      pp[j1] = make_float4(X1, Y1, Z1, 0.f);
      mx[t] = fl2{X0, X1}; my[t] = fl2{Y0, Y1}; mz[t] = fl2{Z0, Z1};
      dist[t] = fl2{__builtin_inff(), __builtin_inff()};
    }
    if (tid == 0)
      __hip_atomic_store(&selstash[b * MB_SEL], 1.0f, __ATOMIC_RELAXED,
                         __HIP_MEMORY_SCOPE_AGENT);   // sel 0, encoded +1
    __syncthreads();

    int cur = 0;
    for (int k = 1; k < MB_SEL; ++k) {
      float4 w = pp[cur];               // one b128 broadcast read
      float bestv = -__builtin_inff();
      int   besti = 0x7fffffff;
#pragma unroll
      for (int t = 0; t < 4; ++t) {
        fl2 dx = mx[t] - w.x;           // v_pk ops; per-comp RN == scalar np
        fl2 dy = my[t] - w.y;
        fl2 dz = mz[t] - w.z;
        fl2 dd = (dx * dx + dy * dy) + dz * dz;   // np order, contract off
        fl2 dc = dist[t];
        float d0 = fminf(dc.x, dd.x);   // np.minimum
        float d1 = fminf(dc.y, dd.y);
        dist[t] = fl2{d0, d1};
        if (d0 > bestv) { bestv = d0; besti = tid + (2 * t) * 512; }
        if (d1 > bestv) { bestv = d1; besti = tid + (2 * t + 1) * 512; }
      }
      // key: larger d wins; tie -> smaller idx (np.argmax first-max)
      ULL key = ((ULL)__float_as_uint(bestv) << 32) | (ULL)(~(UI)besti);
      key = dpp_max_step<0x111>(key);   // row_shr:1
      key = dpp_max_step<0x112>(key);   // row_shr:2
      key = dpp_max_step<0x114>(key);   // row_shr:4
      key = dpp_max_step<0x118>(key);   // row_shr:8
      key = dpp_max_step<0x142>(key);   // row_bcast:15
      key = dpp_max_step<0x143>(key);   // row_bcast:31 -> lane 63 = wave max
      const int buf = (k & 1) * 8;
      if (lane == 63) slots[buf + wv] = key;
      __syncthreads();                  // single barrier (double-buffered)
      const ULL* sp = slots + buf;
      ULL s0 = sp[0], s1 = sp[1], s2 = sp[2], s3 = sp[3];
      ULL s4 = sp[4], s5 = sp[5], s6 = sp[6], s7 = sp[7];
      ULL m01 = s0 > s1 ? s0 : s1;      // tree merge (r14 was a serial loop)
      ULL m23 = s2 > s3 ? s2 : s3;
      ULL m45 = s4 > s5 ? s4 : s5;
      ULL m67 = s6 > s7 ? s6 : s7;
      ULL ma = m01 > m23 ? m01 : m23;
      ULL mb = m45 > m67 ? m45 : m67;
      ULL mk = ma > mb ? ma : mb;
      int winner = (int)(~(UI)mk);
      if (tid == 0)
        __hip_atomic_store(&selstash[b * MB_SEL + k], (float)(winner + 1),
                           __ATOMIC_RELAXED, __HIP_MEMORY_SCOPE_AGENT);
      cur = winner;
    }
    return;
  }

  // ============================ role: conv =================================
  f16* featA  = (f16*)smem;
  f16* h1s    = (f16*)(smem + OFF_H1);
  f16* h2s    = (f16*)(smem + OFF_H2);
  float* pmax = (float*)(smem + OFF_PMAX);
  ULL* masks  = (ULL*)(smem + OFF_MASK);
  int* nbrS   = (int*)(smem + OFF_NBR);
  int* nvP    = (int*)(smem + OFF_NV);
  int* shS    = (int*)(smem + OFF_SHS);

  const int c  = (int)blockIdx.x - (NCLOUD + 1);
  const int k  = c >> 2;
  const int b  = c & 3;
  const int cg = b * MB_SEL + k;     // global centroid id (output index)

  // gate 1: weights ready (release/acquire covers the non-atomic ws payload)
  if (tid == 0) {
    while (__hip_atomic_load(wsflag, __ATOMIC_ACQUIRE,
                             __HIP_MEMORY_SCOPE_AGENT) != WSFLAG_MAGIC)
      __builtin_amdgcn_s_sleep(2);
  }
  __syncthreads();

  // B1/B2 + bias preload (8 waves own 16 cols each for L1/L2, 32 for L3)
  const int n    = lane & 15;
  const int quad = lane >> 4;
  const int col  = wv * 16 + n;       // L1/L2 column
  h8 B1f[3], B2f[4];
  float bv1, bv2, bv3[2];
  bv1 = b1[col];
  bv2 = b2[col];
#pragma unroll
  for (int kt = 0; kt < 3; ++kt)
    B1f[kt] = *(const h8*)(ws + col * 96 + kt * 32 + quad * 8);
#pragma unroll
  for (int kt = 0; kt < 4; ++kt)
    B2f[kt] = *(const h8*)(ws + WT2_OFF + col * 128 + kt * 32 + quad * 8);
#pragma unroll
  for (int ct = 0; ct < 2; ++ct) bv3[ct] = b3[(2 * wv + ct) * 16 + n];

  // gate 2: own sel ready (value IS the payload; winner+1 >= 1;
  // both init states — memset-0 and 0xAA poison — read as "not ready")
  if (tid == 0) {
    float v;
    for (;;) {
      v = __hip_atomic_load(&selstash[cg], __ATOMIC_RELAXED,
                            __HIP_MEMORY_SCOPE_AGENT);
      if (v >= 1.0f) break;
      __builtin_amdgcn_s_sleep(8);
    }
    *shS = (int)v - 1;
  }
  __syncthreads();
  const int s = (*shS) & (NB_PTS - 1);

  const size_t qb = ((size_t)(b * NB_PTS + s)) * 3;
  const float qxf = pos[qb], qyf = pos[qb + 1], qzf = pos[qb + 2];
  const double qx = (double)qxf, qy = (double)qyf, qz = (double)qzf;
  const double RR = 0.2 * 0.2;

  // radius: in-ball bitmask over all 4096 points (f64, np-exact).
  // 8 waves x 8 chunks = 64 chunks of 64 points.
#pragma unroll
  for (int it = 0; it < 8; ++it) {
    const int ch = wv * 8 + it;
    const int j  = ch * 64 + lane;
    const size_t pb = ((size_t)b * NB_PTS + j) * 3;
    double d2 = d2_np64((double)pos[pb] - qx, (double)pos[pb + 1] - qy,
                        (double)pos[pb + 2] - qz);
    ULL m = __ballot(d2 <= RR);
    if (lane == 0) masks[ch] = m;
  }
  __syncthreads();

  // wave 0: first-64 in-ball extraction (ascending index)
  if (tid < 64) {
    ULL m = masks[tid];
    int pc = __popcll(m);
    int incl = pc;
#pragma unroll
    for (int off = 1; off < 64; off <<= 1) {
      int o = __shfl_up(incl, off, 64);
      if (tid >= off) incl += o;
    }
    int base = incl - pc;
    int tot  = __shfl(incl, 63, 64);
    int nvw  = min(tot, KNBR);
    if (tid == 63) *nvP = nvw;
    int slot = base;
    ULL mm = m;
    while (mm && slot < KNBR) {
      int bit = __ffsll(mm) - 1;
      nbrS[slot++] = tid * 64 + bit;
      mm &= mm - 1;
    }
    if (tid >= nvw) nbrS[tid] = s;
  }
  __syncthreads();
  const int nv = *nvP;

  // gather: feat=[x_j, pos_j-pos_i, 0-pad] as f16, rows 0..63 (8 thr/row)
  {
    const int r = tid >> 3;
    const int part = tid & 7;
    const int g = nbrS[r];
    const float* xrow = x + (((size_t)(b * NB_PTS + g)) << 6) + part * 8;
    float4 u0 = *(const float4*)(xrow);
    float4 u1 = *(const float4*)(xrow + 4);
    h8 o0;
    o0[0]=(f16)u0.x; o0[1]=(f16)u0.y; o0[2]=(f16)u0.z; o0[3]=(f16)u0.w;
    o0[4]=(f16)u1.x; o0[5]=(f16)u1.y; o0[6]=(f16)u1.z; o0[7]=(f16)u1.w;
    *(h8*)(featA + r * 104 + part * 8) = o0;
    if (part == 7) {
      size_t gb = ((size_t)(b * NB_PTS + g)) * 3;
      h8 rv = {(f16)0.f,(f16)0.f,(f16)0.f,(f16)0.f,(f16)0.f,(f16)0.f,(f16)0.f,(f16)0.f};
      rv[0] = (f16)(pos[gb]     - qxf);
      rv[1] = (f16)(pos[gb + 1] - qyf);
      rv[2] = (f16)(pos[gb + 2] - qzf);
      h8 z = {(f16)0.f,(f16)0.f,(f16)0.f,(f16)0.f,(f16)0.f,(f16)0.f,(f16)0.f,(f16)0.f};
      *(h8*)(featA + r * 104 + 64) = rv;
      *(h8*)(featA + r * 104 + 72) = z;
      *(h8*)(featA + r * 104 + 80) = z;
      *(h8*)(featA + r * 104 + 88) = z;
    }
  }
  __syncthreads();

  // L1: 67(->96) -> 128 ; wave w owns cols [16w,16w+16)
#pragma unroll
  for (int at = 0; at < 4; ++at) {
    f32x4 acc = {0.f, 0.f, 0.f, 0.f};
#pragma unroll
    for (int kt = 0; kt < 3; ++kt) {
      h8 a = *(const h8*)(featA + (at * 16 + n) * 104 + kt * 32 + quad * 8);
      acc = __builtin_amdgcn_mfma_f32_16x16x32_f16(a, B1f[kt], acc, 0, 0, 0);
    }
#pragma unroll
    for (int r = 0; r < 4; ++r)
      h1s[(at * 16 + quad * 4 + r) * 136 + col] = (f16)fmaxf(acc[r] + bv1, 0.f);
  }
  __syncthreads();

  // L2: 128 -> 128
#pragma unroll
  for (int at = 0; at < 4; ++at) {
    f32x4 acc = {0.f, 0.f, 0.f, 0.f};
#pragma unroll
    for (int kt = 0; kt < 4; ++kt) {
      h8 a = *(const h8*)(h1s + (at * 16 + n) * 136 + kt * 32 + quad * 8);
      acc = __builtin_amdgcn_mfma_f32_16x16x32_f16(a, B2f[kt], acc, 0, 0, 0);
    }
#pragma unroll
    for (int r = 0; r < 4; ++r)
      h2s[(at * 16 + quad * 4 + r) * 136 + col] = (f16)fmaxf(acc[r] + bv2, 0.f);
  }
  __syncthreads();

  // L3: 128 -> 256, wave w owns cols [32w,32w+32); B3 streamed from L2
  float vm[2] = {0.f, 0.f};   // valid max >= 0 (relu, nv>=1)
#pragma unroll
  for (int at = 0; at < 4; ++at) {
#pragma unroll
    for (int ct = 0; ct < 2; ++ct) {
      const int c3 = (2 * wv + ct) * 16 + n;
      f32x4 acc = {0.f, 0.f, 0.f, 0.f};
#pragma unroll
      for (int kt = 0; kt < 4; ++kt) {
        h8 a = *(const h8*)(h2s + (at * 16 + n) * 136 + kt * 32 + quad * 8);
        h8 wfr = *(const h8*)(ws + WT3_OFF + c3 * 128 + kt * 32 + quad * 8);
        acc = __builtin_amdgcn_mfma_f32_16x16x32_f16(a, wfr, acc, 0, 0, 0);
      }
#pragma unroll
      for (int r = 0; r < 4; ++r) {
        float h = fmaxf(acc[r] + bv3[ct], 0.f);
        const int row = at * 16 + quad * 4 + r;
        vm[ct] = fmaxf(vm[ct], row < nv ? h : 0.f);
      }
    }
  }
#pragma unroll
  for (int ct = 0; ct < 2; ++ct) {
    vm[ct] = fmaxf(vm[ct], __shfl_xor(vm[ct], 16, 64));
    vm[ct] = fmaxf(vm[ct], __shfl_xor(vm[ct], 32, 64));
  }
  if (quad == 0) {
#pragma unroll
    for (int ct = 0; ct < 2; ++ct) pmax[(2 * wv + ct) * 16 + n] = vm[ct];
  }
  __syncthreads();

  if (tid < 256) out_x[(size_t)cg * 256 + tid] = pmax[tid];
  if (tid < 3) out_pos[cg * 3 + tid] = pos[qb + tid];
  if (tid == 0) out_batch[cg] = (float)b;   // overwrite sel stash
}

extern "C" void kernel_launch(void* const* d_in, const int* in_sizes, int n_in,
                              void* d_out, int out_size, void* d_ws, size_t ws_size,
                              hipStream_t stream) {
  const float* x   = (const float*)d_in[0];
  const float* pos = (const float*)d_in[1];
  // d_in[2] = batch (int32), unused (layout known)
  const float* W1 = (const float*)d_in[3];
  const float* b1 = (const float*)d_in[4];
  const float* W2 = (const float*)d_in[5];
  const float* b2 = (const float*)d_in[6];
  const float* W3 = (const float*)d_in[7];
  const float* b3 = (const float*)d_in[8];

  float* out = (float*)d_out;
  float* out_pos   = out + (size_t)NCENT * 256;
  float* out_batch = out_pos + (size_t)NCENT * 3;   // doubles as sel channel
  f16* ws    = (f16*)d_ws;                          // 122880 B f16 weights
  UI* wsflag = (UI*)((char*)d_ws + 2 * WS_ELEMS);   // publish flag

  // opt-in to >64 KB dynamic LDS (idempotent; host-side, capture-safe)
  hipFuncSetAttribute((const void*)fused_kernel,
                      hipFuncAttributeMaxDynamicSharedMemorySize, DYN_LDS);

  fused_kernel<<<NCLOUD + 1 + NCENT, 512, DYN_LDS, stream>>>(
      x, pos, W1, b1, W2, b2, W3, b3, ws, wsflag,
      out_batch, out, out_pos, out_batch);
}